// Round 1
// baseline (723.499 us; speedup 1.0000x reference)
//
#include <hip/hip_runtime.h>
#include <math.h>

#define D 768
#define NH 8
#define HD 96
#define NW 16
#define OVL 32
#define NLINES 8192
#define NCOMB (NLINES + 2 * OVL)  // 8256

#define BM 64
#define BN 64
#define BK 32
#define PAD 4  // keep rows 16B-aligned (stride 68 floats = 272 B)

__device__ __forceinline__ const float* comb_row(const float* main_, const float* begin_,
                                                 const float* end_, int r) {
    if (r < OVL) return begin_ + (size_t)r * D;
    if (r < OVL + NLINES) return main_ + (size_t)(r - OVL) * D;
    return end_ + (size_t)(r - OVL - NLINES) * D;
}

// z = 0: Q = scale*(main @ wq.T + bq)   M = 8192
// z = 1: K = combined @ wk.T + bk       M = 8256
// z = 2: V = combined @ wv.T + bv       M = 8256
__global__ __launch_bounds__(256) void qkv_gemm(const float* __restrict__ main_,
                                                const float* __restrict__ begin_,
                                                const float* __restrict__ end_,
                                                const float* __restrict__ w_all,
                                                const float* __restrict__ b_all,
                                                float* __restrict__ Q,
                                                float* __restrict__ Kall,
                                                float* __restrict__ Vall) {
    const int z = blockIdx.z;
    const int M = (z == 0) ? NLINES : NCOMB;
    const int m0 = blockIdx.y * BM;
    if (m0 >= M) return;  // uniform across block
    const int n0 = blockIdx.x * BN;
    const float* W = w_all + (size_t)z * D * D;
    const float* bias = b_all + z * D;
    float* Cout = (z == 0) ? Q : (z == 1 ? Kall : Vall);
    const float scale = (z == 0) ? 0.1020620726159657f : 1.0f;  // 96^-0.5

    __shared__ float As[BK][BM + PAD];
    __shared__ float Bs[BK][BN + PAD];

    const int tid = threadIdx.x;
    const int tx = tid & 15;   // n sub-tile
    const int ty = tid >> 4;   // m sub-tile
    const int lr = tid >> 3;   // 0..31 load row
    const int lc = tid & 7;    // 0..7  -> k offset lc*4

    float acc[4][4] = {};

    for (int k0 = 0; k0 < D; k0 += BK) {
#pragma unroll
        for (int l = 0; l < 2; l++) {
            const int r = lr + 32 * l;
            // A tile (gathered rows), transposed into As[k][m]
            const int grow = m0 + r;
            float4 av = make_float4(0.f, 0.f, 0.f, 0.f);
            if (grow < M) {
                const float* src = (z == 0) ? (main_ + (size_t)grow * D)
                                            : comb_row(main_, begin_, end_, grow);
                av = *(const float4*)(src + k0 + lc * 4);
            }
            As[lc * 4 + 0][r] = av.x;
            As[lc * 4 + 1][r] = av.y;
            As[lc * 4 + 2][r] = av.z;
            As[lc * 4 + 3][r] = av.w;
            // B tile: W[n0+r][k0 + lc*4 ..], transposed into Bs[k][n]
            const float4 wv = *(const float4*)(W + (size_t)(n0 + r) * D + k0 + lc * 4);
            Bs[lc * 4 + 0][r] = wv.x;
            Bs[lc * 4 + 1][r] = wv.y;
            Bs[lc * 4 + 2][r] = wv.z;
            Bs[lc * 4 + 3][r] = wv.w;
        }
        __syncthreads();
#pragma unroll
        for (int kk = 0; kk < BK; kk++) {
            float a[4], b[4];
            *(float4*)a = *(const float4*)&As[kk][ty * 4];
            *(float4*)b = *(const float4*)&Bs[kk][tx * 4];
#pragma unroll
            for (int i = 0; i < 4; i++)
#pragma unroll
                for (int j = 0; j < 4; j++) acc[i][j] += a[i] * b[j];
        }
        __syncthreads();
    }

#pragma unroll
    for (int i = 0; i < 4; i++) {
        const int row = m0 + ty * 4 + i;
        if (row >= M) continue;
#pragma unroll
        for (int j = 0; j < 4; j++) {
            const int col = n0 + tx * 4 + j;
            Cout[(size_t)row * D + col] = (acc[i][j] + bias[col]) * scale;
        }
    }
}

// One block per line n. 128 threads = 8 heads x 16 window slots.
__global__ __launch_bounds__(128) void attn_kernel(const float* __restrict__ Q,
                                                   const float* __restrict__ K,
                                                   const float* __restrict__ V,
                                                   float* __restrict__ ctx) {
    const int n = blockIdx.x;
    const int tid = threadIdx.x;
    const int h = tid >> 4;
    const int w = tid & 15;

    __shared__ float s_attn[NH][NW];
    __shared__ int s_row[NW];

    const int off = (w < 8) ? (w - 8) * 4 : (w - 7) * 4;  // -32..-4, 4..32
    const int row = n + OVL + off;
    if (h == 0) s_row[w] = row;

    // scores[h][w] = q[n,h,:] . k[row,h,:]   (Q already pre-scaled by 96^-0.5)
    const float* qp = Q + (size_t)n * D + h * HD;
    const float* kp = K + (size_t)row * D + h * HD;
    float s = 0.f;
#pragma unroll
    for (int d = 0; d < HD; d += 4) {
        const float4 a = *(const float4*)(qp + d);
        const float4 b = *(const float4*)(kp + d);
        s += a.x * b.x + a.y * b.y + a.z * b.z + a.w * b.w;
    }
    s_attn[h][w] = s;
    __syncthreads();

    if (tid < NH) {
        const int hh = tid;
        float mx = -1e30f;
#pragma unroll
        for (int i = 0; i < NW; i++) mx = fmaxf(mx, s_attn[hh][i]);
        float e[NW];
        float sum = 0.f;
#pragma unroll
        for (int i = 0; i < NW; i++) {
            e[i] = expf(s_attn[hh][i] - mx);
            sum += e[i];
        }
        const float inv = 1.f / sum;
#pragma unroll
        for (int i = 0; i < NW; i++) s_attn[hh][i] = e[i] * inv;
    }
    __syncthreads();

    // ctx[n, e] = sum_w attn[h(e)][w] * V[row_w][e]; 768 dims / 128 threads = 6 each
    for (int e = tid; e < D; e += 128) {
        const int hh = e / HD;
        float acc = 0.f;
#pragma unroll
        for (int i = 0; i < NW; i++) acc += s_attn[hh][i] * V[(size_t)s_row[i] * D + e];
        ctx[(size_t)n * D + e] = acc;
    }
}

// attn_out = ctx @ out_w.T + out_b, written to out[:, 768:1536] (row stride 1536)
__global__ __launch_bounds__(256) void out_gemm(const float* __restrict__ A,
                                                const float* __restrict__ W,
                                                const float* __restrict__ bias,
                                                float* __restrict__ out) {
    const int m0 = blockIdx.y * BM;
    const int n0 = blockIdx.x * BN;

    __shared__ float As[BK][BM + PAD];
    __shared__ float Bs[BK][BN + PAD];

    const int tid = threadIdx.x;
    const int tx = tid & 15;
    const int ty = tid >> 4;
    const int lr = tid >> 3;
    const int lc = tid & 7;

    float acc[4][4] = {};

    for (int k0 = 0; k0 < D; k0 += BK) {
#pragma unroll
        for (int l = 0; l < 2; l++) {
            const int r = lr + 32 * l;
            const float4 av = *(const float4*)(A + (size_t)(m0 + r) * D + k0 + lc * 4);
            As[lc * 4 + 0][r] = av.x;
            As[lc * 4 + 1][r] = av.y;
            As[lc * 4 + 2][r] = av.z;
            As[lc * 4 + 3][r] = av.w;
            const float4 wv = *(const float4*)(W + (size_t)(n0 + r) * D + k0 + lc * 4);
            Bs[lc * 4 + 0][r] = wv.x;
            Bs[lc * 4 + 1][r] = wv.y;
            Bs[lc * 4 + 2][r] = wv.z;
            Bs[lc * 4 + 3][r] = wv.w;
        }
        __syncthreads();
#pragma unroll
        for (int kk = 0; kk < BK; kk++) {
            float a[4], b[4];
            *(float4*)a = *(const float4*)&As[kk][ty * 4];
            *(float4*)b = *(const float4*)&Bs[kk][tx * 4];
#pragma unroll
            for (int i = 0; i < 4; i++)
#pragma unroll
                for (int j = 0; j < 4; j++) acc[i][j] += a[i] * b[j];
        }
        __syncthreads();
    }

#pragma unroll
    for (int i = 0; i < 4; i++) {
        const int row = m0 + ty * 4 + i;
#pragma unroll
        for (int j = 0; j < 4; j++) {
            const int col = n0 + tx * 4 + j;
            out[(size_t)row * (2 * D) + D + col] = acc[i][j] + bias[col];
        }
    }
}

// out[:, 0:768] = main (float4 copy)
__global__ __launch_bounds__(256) void copy_main(const float* __restrict__ main_,
                                                 float* __restrict__ out) {
    const int i = blockIdx.x * blockDim.x + threadIdx.x;  // over 8192*192 float4
    const int row = i / (D / 4);
    const int c4 = i % (D / 4);
    ((float4*)out)[(size_t)row * (2 * D / 4) + c4] = ((const float4*)main_)[i];
}

extern "C" void kernel_launch(void* const* d_in, const int* in_sizes, int n_in,
                              void* d_out, int out_size, void* d_ws, size_t ws_size,
                              hipStream_t stream) {
    const float* main_ = (const float*)d_in[0];
    const float* begin_ = (const float*)d_in[1];
    const float* end_ = (const float*)d_in[2];
    const float* in_w = (const float*)d_in[3];
    const float* in_b = (const float*)d_in[4];
    const float* out_w = (const float*)d_in[5];
    const float* out_b = (const float*)d_in[6];
    float* out = (float*)d_out;

    float* Q = (float*)d_ws;                    // 8192*768
    float* K = Q + (size_t)NLINES * D;          // 8256*768
    float* V = K + (size_t)NCOMB * D;           // 8256*768
    float* ctx = V + (size_t)NCOMB * D;         // 8192*768
    // total: 101 MB of d_ws

    qkv_gemm<<<dim3(D / BN, (NCOMB + BM - 1) / BM, 3), 256, 0, stream>>>(
        main_, begin_, end_, in_w, in_b, Q, K, V);
    attn_kernel<<<NLINES, 128, 0, stream>>>(Q, K, V, ctx);
    out_gemm<<<dim3(D / BN, NLINES / BM), 256, 0, stream>>>(ctx, out_w, out_b, out);
    copy_main<<<(NLINES * (D / 4)) / 256, 256, 0, stream>>>(main_, out);
}

// Round 2
// 224.766 us; speedup vs baseline: 3.2189x; 3.2189x over previous
//
#include <hip/hip_runtime.h>
#include <math.h>

#define D 768
#define NH 8
#define HD 96
#define NW 16
#define OVL 32
#define NLINES 8192
#define NCOMB 8256
#define MPAD 8320  // 65 * 128, zero-padded rows for guard-free GEMM

typedef __bf16 bf16x8 __attribute__((ext_vector_type(8)));
typedef float f32x4 __attribute__((ext_vector_type(4)));

__device__ __forceinline__ unsigned short f2bf(float f) {
    unsigned int u = __float_as_uint(f);
    u += 0x7FFF + ((u >> 16) & 1);  // RNE
    return (unsigned short)(u >> 16);
}
__device__ __forceinline__ float bflo(unsigned int u) { return __uint_as_float(u << 16); }
__device__ __forceinline__ float bfhi(unsigned int u) { return __uint_as_float(u & 0xFFFF0000u); }

__device__ __forceinline__ void stage16(const unsigned short* g, unsigned short* l) {
    __builtin_amdgcn_global_load_lds(
        (const __attribute__((address_space(1))) unsigned int*)g,
        (__attribute__((address_space(3))) unsigned int*)l, 16, 0, 0);
}

// ---- fp32 -> bf16 converts -------------------------------------------------

// combined = [begin; main; end] padded to MPAD rows with zeros, as bf16
__global__ __launch_bounds__(256) void convert_comb(const float* __restrict__ main_,
                                                    const float* __restrict__ begin_,
                                                    const float* __restrict__ end_,
                                                    unsigned short* __restrict__ dst) {
    const int i = blockIdx.x * 256 + threadIdx.x;  // over MPAD*192 float4 groups
    const int row = i / 192;
    const int c = (i % 192) * 4;
    float4 v = make_float4(0.f, 0.f, 0.f, 0.f);
    if (row < NCOMB) {
        const float* src = (row < OVL) ? begin_ + (size_t)row * D
                         : (row < OVL + NLINES) ? main_ + (size_t)(row - OVL) * D
                                                : end_ + (size_t)(row - OVL - NLINES) * D;
        v = *(const float4*)(src + c);
    }
    ushort4 o;
    o.x = f2bf(v.x); o.y = f2bf(v.y); o.z = f2bf(v.z); o.w = f2bf(v.w);
    *(ushort4*)(dst + (size_t)row * D + c) = o;
}

__global__ __launch_bounds__(256) void convert_f2bf(const float* __restrict__ src,
                                                    unsigned short* __restrict__ dst) {
    const int i = (blockIdx.x * 256 + threadIdx.x) * 4;
    const float4 v = *(const float4*)(src + i);
    ushort4 o;
    o.x = f2bf(v.x); o.y = f2bf(v.y); o.z = f2bf(v.z); o.w = f2bf(v.w);
    *(ushort4*)(dst + i) = o;
}

// ---- 128x128 MFMA GEMM tile: C = A @ B^T (+bias)*scale ---------------------
// A: Mx768 bf16 row-major, B: 128-col slice of (Nx768) bf16 row-major.
template <bool BF16OUT>
__device__ __forceinline__ void gemm_tile(const unsigned short* __restrict__ A,
                                          const unsigned short* __restrict__ B,
                                          const float* __restrict__ bias,
                                          void* __restrict__ Cout, int ldc, int col_off,
                                          float scale, int m0, int n0) {
    __shared__ __align__(16) unsigned short As[128 * 32];
    __shared__ __align__(16) unsigned short Bs[128 * 32];
    const int tid = threadIdx.x;
    const int lane = tid & 63;
    const int wave = tid >> 6;
    const int wm = (wave & 1) * 64;
    const int wn = (wave >> 1) * 64;
    const int q = lane >> 4;    // quad
    const int l15 = lane & 15;

    const int srow = tid >> 2;        // 0..63 staging row
    const int scol = (tid & 3) * 8;   // k element offset

    f32x4 acc[4][4] = {};

    for (int k0 = 0; k0 < D; k0 += 32) {
        stage16(A + (size_t)(m0 + srow) * D + k0 + scol, As + tid * 8);
        stage16(A + (size_t)(m0 + 64 + srow) * D + k0 + scol, As + 2048 + tid * 8);
        stage16(B + (size_t)(n0 + srow) * D + k0 + scol, Bs + tid * 8);
        stage16(B + (size_t)(n0 + 64 + srow) * D + k0 + scol, Bs + 2048 + tid * 8);
        __syncthreads();  // vmcnt(0) drain + barrier
        bf16x8 af[4], bfr[4];
#pragma unroll
        for (int i = 0; i < 4; i++)
            af[i] = *(const bf16x8*)(As + (wm + i * 16 + l15) * 32 + q * 8);
#pragma unroll
        for (int j = 0; j < 4; j++)
            bfr[j] = *(const bf16x8*)(Bs + (wn + j * 16 + l15) * 32 + q * 8);
#pragma unroll
        for (int i = 0; i < 4; i++)
#pragma unroll
            for (int j = 0; j < 4; j++)
                acc[i][j] = __builtin_amdgcn_mfma_f32_16x16x32_bf16(af[i], bfr[j], acc[i][j], 0, 0, 0);
        __syncthreads();
    }

#pragma unroll
    for (int i = 0; i < 4; i++) {
#pragma unroll
        for (int j = 0; j < 4; j++) {
#pragma unroll
            for (int r = 0; r < 4; r++) {
                const int row = m0 + wm + i * 16 + q * 4 + r;  // C row = quad*4+reg
                const int col = n0 + wn + j * 16 + l15;        // C col = lane&15
                const float v = (acc[i][j][r] + bias[col]) * scale;
                if (BF16OUT)
                    ((unsigned short*)Cout)[(size_t)row * ldc + col_off + col] = f2bf(v);
                else
                    ((float*)Cout)[(size_t)row * ldc + col_off + col] = v;
            }
        }
    }
}

// z=0: Q (8192 rows, scaled), z=1: K, z=2: V (8320 padded rows)
__global__ __launch_bounds__(256) void qkv_gemm(const unsigned short* __restrict__ comb,
                                                const unsigned short* __restrict__ w_bf,
                                                const float* __restrict__ b_all,
                                                unsigned short* __restrict__ Q,
                                                unsigned short* __restrict__ K,
                                                unsigned short* __restrict__ V) {
    const int z = blockIdx.z;
    const int mt = blockIdx.y;
    if (z == 0 && mt == 64) return;  // Q has only 64 M-tiles (uniform exit)
    const unsigned short* A = (z == 0) ? comb + (size_t)OVL * D : comb;
    const unsigned short* B = w_bf + (size_t)z * D * D;
    unsigned short* C = (z == 0) ? Q : (z == 1 ? K : V);
    const float scale = (z == 0) ? 0.1020620726159657f : 1.0f;  // 96^-0.5
    gemm_tile<true>(A, B, b_all + z * D, C, D, 0, scale, mt * 128, blockIdx.x * 128);
}

__global__ __launch_bounds__(256) void out_gemm(const unsigned short* __restrict__ ctx,
                                                const unsigned short* __restrict__ w,
                                                const float* __restrict__ bias,
                                                float* __restrict__ out) {
    gemm_tile<false>(ctx, w, bias, out, 2 * D, D, 1.0f, blockIdx.y * 128, blockIdx.x * 128);
}

// ---- attention: one block per line, 8 heads x 16 window slots --------------
__global__ __launch_bounds__(128) void attn_kernel(const unsigned short* __restrict__ Q,
                                                   const unsigned short* __restrict__ K,
                                                   const unsigned short* __restrict__ V,
                                                   unsigned short* __restrict__ ctx) {
    const int n = blockIdx.x;
    const int tid = threadIdx.x;
    const int h = tid >> 4;
    const int w = tid & 15;

    __shared__ float s_attn[NH][NW];
    __shared__ int s_row[NW];

    const int off = (w < 8) ? (w - 8) * 4 : (w - 7) * 4;  // -32..-4, 4..32 step 4
    const int row = n + OVL + off;
    if (h == 0) s_row[w] = row;

    const unsigned short* qp = Q + (size_t)n * D + h * HD;
    const unsigned short* kp = K + (size_t)row * D + h * HD;
    float s = 0.f;
#pragma unroll
    for (int d = 0; d < HD; d += 8) {
        const uint4 qa = *(const uint4*)(qp + d);
        const uint4 ka = *(const uint4*)(kp + d);
        s += bflo(qa.x) * bflo(ka.x) + bfhi(qa.x) * bfhi(ka.x);
        s += bflo(qa.y) * bflo(ka.y) + bfhi(qa.y) * bfhi(ka.y);
        s += bflo(qa.z) * bflo(ka.z) + bfhi(qa.z) * bfhi(ka.z);
        s += bflo(qa.w) * bflo(ka.w) + bfhi(qa.w) * bfhi(ka.w);
    }
    s_attn[h][w] = s;
    __syncthreads();

    if (tid < NH) {
        const int hh = tid;
        float mx = -1e30f;
#pragma unroll
        for (int i = 0; i < NW; i++) mx = fmaxf(mx, s_attn[hh][i]);
        float e[NW], sum = 0.f;
#pragma unroll
        for (int i = 0; i < NW; i++) {
            e[i] = __expf(s_attn[hh][i] - mx);
            sum += e[i];
        }
        const float inv = 1.f / sum;
#pragma unroll
        for (int i = 0; i < NW; i++) s_attn[hh][i] = e[i] * inv;
    }
    __syncthreads();

    // ctx: 384 element-pairs / 128 threads = 3 pairs each (pairs never cross heads)
#pragma unroll
    for (int it = 0; it < 3; it++) {
        const int p = tid + it * 128;
        const int e = p * 2;
        const int hh = e / HD;
        float a0 = 0.f, a1 = 0.f;
#pragma unroll
        for (int i = 0; i < NW; i++) {
            const unsigned int vu = *(const unsigned int*)(V + (size_t)s_row[i] * D + e);
            const float aw = s_attn[hh][i];
            a0 += aw * bflo(vu);
            a1 += aw * bfhi(vu);
        }
        *(unsigned int*)(ctx + (size_t)n * D + e) =
            (unsigned int)f2bf(a0) | ((unsigned int)f2bf(a1) << 16);
    }
}

// out[:, 0:768] = main (exact fp32 copy)
__global__ __launch_bounds__(256) void copy_main(const float* __restrict__ main_,
                                                 float* __restrict__ out) {
    const int i = blockIdx.x * blockDim.x + threadIdx.x;  // 8192*192 float4
    const int row = i / (D / 4);
    const int c4 = i % (D / 4);
    ((float4*)out)[(size_t)row * (2 * D / 4) + c4] = ((const float4*)main_)[i];
}

extern "C" void kernel_launch(void* const* d_in, const int* in_sizes, int n_in,
                              void* d_out, int out_size, void* d_ws, size_t ws_size,
                              hipStream_t stream) {
    const float* main_ = (const float*)d_in[0];
    const float* begin_ = (const float*)d_in[1];
    const float* end_ = (const float*)d_in[2];
    const float* in_w = (const float*)d_in[3];
    const float* in_b = (const float*)d_in[4];
    const float* out_w = (const float*)d_in[5];
    const float* out_b = (const float*)d_in[6];
    float* out = (float*)d_out;

    // workspace (bf16 elements), all offsets 16B-aligned; total ~68 MB
    unsigned short* comb_bf = (unsigned short*)d_ws;        // MPAD*D
    unsigned short* w_bf = comb_bf + (size_t)MPAD * D;      // 3*D*D
    unsigned short* wo_bf = w_bf + (size_t)3 * D * D;       // D*D
    unsigned short* Qb = wo_bf + (size_t)D * D;             // NLINES*D
    unsigned short* Kb = Qb + (size_t)NLINES * D;           // MPAD*D
    unsigned short* Vb = Kb + (size_t)MPAD * D;             // MPAD*D
    unsigned short* ctxb = Vb + (size_t)MPAD * D;           // NLINES*D

    convert_comb<<<MPAD * (D / 4) / 256, 256, 0, stream>>>(main_, begin_, end_, comb_bf);
    convert_f2bf<<<3 * D * D / 1024, 256, 0, stream>>>(in_w, w_bf);
    convert_f2bf<<<D * D / 1024, 256, 0, stream>>>(out_w, wo_bf);
    qkv_gemm<<<dim3(D / 128, MPAD / 128, 3), 256, 0, stream>>>(comb_bf, w_bf, in_b, Qb, Kb, Vb);
    attn_kernel<<<NLINES, 128, 0, stream>>>(Qb, Kb, Vb, ctxb);
    out_gemm<<<dim3(D / 128, NLINES / 128), 256, 0, stream>>>(ctxb, wo_bf, out_b, out);
    copy_main<<<NLINES * (D / 4) / 256, 256, 0, stream>>>(main_, out);
}

// Round 3
// 199.237 us; speedup vs baseline: 3.6314x; 1.1281x over previous
//
#include <hip/hip_runtime.h>
#include <math.h>

#define D 768
#define NH 8
#define HD 96
#define NW 16
#define OVL 32
#define NLINES 8192
#define NCOMB 8256
#define MPAD 8320  // 65 * 128, zero-padded rows for guard-free GEMM
#define CH 64      // attention lines per block

typedef __bf16 bf16x8 __attribute__((ext_vector_type(8)));
typedef float f32x4 __attribute__((ext_vector_type(4)));

__device__ __forceinline__ unsigned short f2bf(float f) {
    unsigned int u = __float_as_uint(f);
    u += 0x7FFF + ((u >> 16) & 1);  // RNE
    return (unsigned short)(u >> 16);
}
__device__ __forceinline__ float bflo(unsigned int u) { return __uint_as_float(u << 16); }
__device__ __forceinline__ float bfhi(unsigned int u) { return __uint_as_float(u & 0xFFFF0000u); }

__device__ __forceinline__ void stage16(const unsigned short* g, unsigned short* l) {
    __builtin_amdgcn_global_load_lds(
        (const __attribute__((address_space(1))) unsigned int*)g,
        (__attribute__((address_space(3))) unsigned int*)l, 16, 0, 0);
}

// ---- fp32 -> bf16 converts -------------------------------------------------

__global__ __launch_bounds__(256) void convert_comb(const float* __restrict__ main_,
                                                    const float* __restrict__ begin_,
                                                    const float* __restrict__ end_,
                                                    unsigned short* __restrict__ dst) {
    const int i = blockIdx.x * 256 + threadIdx.x;  // MPAD*192 float4 groups
    const int row = i / 192;
    const int c = (i % 192) * 4;
    float4 v = make_float4(0.f, 0.f, 0.f, 0.f);
    if (row < NCOMB) {
        const float* src = (row < OVL) ? begin_ + (size_t)row * D
                         : (row < OVL + NLINES) ? main_ + (size_t)(row - OVL) * D
                                                : end_ + (size_t)(row - OVL - NLINES) * D;
        v = *(const float4*)(src + c);
    }
    ushort4 o;
    o.x = f2bf(v.x); o.y = f2bf(v.y); o.z = f2bf(v.z); o.w = f2bf(v.w);
    *(ushort4*)(dst + (size_t)row * D + c) = o;
}

__global__ __launch_bounds__(256) void convert_f2bf(const float* __restrict__ src,
                                                    unsigned short* __restrict__ dst) {
    const int i = (blockIdx.x * 256 + threadIdx.x) * 4;
    const float4 v = *(const float4*)(src + i);
    ushort4 o;
    o.x = f2bf(v.x); o.y = f2bf(v.y); o.z = f2bf(v.z); o.w = f2bf(v.w);
    *(ushort4*)(dst + i) = o;
}

// ---- 128x128 MFMA GEMM tile: C = (A @ B^T + bias) * scale ------------------
template <bool BF16OUT>
__device__ __forceinline__ void gemm_tile(const unsigned short* __restrict__ A,
                                          const unsigned short* __restrict__ B,
                                          const float* __restrict__ bias,
                                          void* __restrict__ Cout, int ldc, int col_off,
                                          float scale, int m0, int n0) {
    __shared__ __align__(16) unsigned short As[128 * 32];
    __shared__ __align__(16) unsigned short Bs[128 * 32];
    const int tid = threadIdx.x;
    const int lane = tid & 63;
    const int wave = tid >> 6;
    const int wm = (wave & 1) * 64;
    const int wn = (wave >> 1) * 64;
    const int q = lane >> 4;
    const int l15 = lane & 15;

    const int srow = tid >> 2;
    const int scol = (tid & 3) * 8;

    f32x4 acc[4][4] = {};

    for (int k0 = 0; k0 < D; k0 += 32) {
        stage16(A + (size_t)(m0 + srow) * D + k0 + scol, As + tid * 8);
        stage16(A + (size_t)(m0 + 64 + srow) * D + k0 + scol, As + 2048 + tid * 8);
        stage16(B + (size_t)(n0 + srow) * D + k0 + scol, Bs + tid * 8);
        stage16(B + (size_t)(n0 + 64 + srow) * D + k0 + scol, Bs + 2048 + tid * 8);
        __syncthreads();
        bf16x8 af[4], bfr[4];
#pragma unroll
        for (int i = 0; i < 4; i++)
            af[i] = *(const bf16x8*)(As + (wm + i * 16 + l15) * 32 + q * 8);
#pragma unroll
        for (int j = 0; j < 4; j++)
            bfr[j] = *(const bf16x8*)(Bs + (wn + j * 16 + l15) * 32 + q * 8);
#pragma unroll
        for (int i = 0; i < 4; i++)
#pragma unroll
            for (int j = 0; j < 4; j++)
                acc[i][j] = __builtin_amdgcn_mfma_f32_16x16x32_bf16(af[i], bfr[j], acc[i][j], 0, 0, 0);
        __syncthreads();
    }

#pragma unroll
    for (int i = 0; i < 4; i++) {
#pragma unroll
        for (int j = 0; j < 4; j++) {
#pragma unroll
            for (int r = 0; r < 4; r++) {
                const int row = m0 + wm + i * 16 + q * 4 + r;
                const int col = n0 + wn + j * 16 + l15;
                const float v = (acc[i][j][r] + bias[col]) * scale;
                if (BF16OUT)
                    ((unsigned short*)Cout)[(size_t)row * ldc + col_off + col] = f2bf(v);
                else
                    ((float*)Cout)[(size_t)row * ldc + col_off + col] = v;
            }
        }
    }
}

__global__ __launch_bounds__(256) void qkv_gemm(const unsigned short* __restrict__ comb,
                                                const unsigned short* __restrict__ w_bf,
                                                const float* __restrict__ b_all,
                                                unsigned short* __restrict__ Q,
                                                unsigned short* __restrict__ K,
                                                unsigned short* __restrict__ V) {
    const int z = blockIdx.z;
    const int mt = blockIdx.y;
    if (z == 0 && mt == 64) return;
    const unsigned short* A = (z == 0) ? comb + (size_t)OVL * D : comb;
    const unsigned short* B = w_bf + (size_t)z * D * D;
    unsigned short* C = (z == 0) ? Q : (z == 1 ? K : V);
    const float scale = (z == 0) ? 0.1020620726159657f : 1.0f;  // 96^-0.5
    gemm_tile<true>(A, B, b_all + z * D, C, D, 0, scale, mt * 128, blockIdx.x * 128);
}

// out_gemm + fused main-tile copy into out[:, 0:768]
__global__ __launch_bounds__(256) void out_gemm(const unsigned short* __restrict__ ctx,
                                                const unsigned short* __restrict__ w,
                                                const float* __restrict__ bias,
                                                const float* __restrict__ main_,
                                                float* __restrict__ out) {
    const int m0 = blockIdx.y * 128;
    const int n0 = blockIdx.x * 128;
    gemm_tile<false>(ctx, w, bias, out, 2 * D, D, 1.0f, m0, n0);
    const int tid = threadIdx.x;
#pragma unroll
    for (int it = 0; it < 16; it++) {
        const int idx = tid + it * 256;  // 128 rows x 32 float4
        const int r = idx >> 5, c4 = idx & 31;
        const float4 v = *(const float4*)(main_ + (size_t)(m0 + r) * D + n0 + c4 * 4);
        *(float4*)(out + (size_t)(m0 + r) * (2 * D) + n0 + c4 * 4) = v;
    }
}

// ---- attention: block = 64-line chunk x 1 head, LDS-staged -----------------
__global__ __launch_bounds__(256) void attn_kernel(const unsigned short* __restrict__ Q,
                                                   const unsigned short* __restrict__ K,
                                                   const unsigned short* __restrict__ V,
                                                   unsigned short* __restrict__ ctx) {
    const int n0 = blockIdx.x * CH;
    const int h = blockIdx.y;
    const int tid = threadIdx.x;

    // stride 104 elems (208 B): 52 dwords/row -> lane-bank step 20 mod 32
    // covers all 32 banks for b128 row-major reads (no >2-way conflicts)
    __shared__ __align__(16) unsigned short sQ[CH * 104];    // reused as sO
    __shared__ __align__(16) unsigned short sK[128 * 104];
    __shared__ __align__(16) unsigned short sV[128 * 104];
    __shared__ float sS[CH][17];

    // load Q slice: 64 rows x 12 uint4
#pragma unroll
    for (int it = 0; it < 3; it++) {
        const int idx = tid + it * 256;
        const int row = idx / 12, c = idx % 12;
        *(uint4*)(sQ + row * 104 + c * 8) =
            *(const uint4*)(Q + (size_t)(n0 + row) * D + h * HD + c * 8);
    }
    // load K,V slices: rows n0..n0+127 (exactly the window span), 128 x 12 uint4
#pragma unroll
    for (int it = 0; it < 6; it++) {
        const int idx = tid + it * 256;
        const int row = idx / 12, c = idx % 12;
        *(uint4*)(sK + row * 104 + c * 8) =
            *(const uint4*)(K + (size_t)(n0 + row) * D + h * HD + c * 8);
        *(uint4*)(sV + row * 104 + c * 8) =
            *(const uint4*)(V + (size_t)(n0 + row) * D + h * HD + c * 8);
    }
    __syncthreads();

    const int l = tid & 63;
    const int wg = tid >> 6;

    // scores: thread (l, wg) handles window slots wg*4..wg*4+3
    uint4 qreg[12];
#pragma unroll
    for (int c = 0; c < 12; c++) qreg[c] = *(const uint4*)(sQ + l * 104 + c * 8);
#pragma unroll
    for (int wi = 0; wi < 4; wi++) {
        const int w = wg * 4 + wi;
        const int lrow = l + 4 * w + (w >= 8 ? 4 : 0);  // local K row
        float s = 0.f;
#pragma unroll
        for (int c = 0; c < 12; c++) {
            const uint4 kv = *(const uint4*)(sK + lrow * 104 + c * 8);
            s += bflo(qreg[c].x) * bflo(kv.x) + bfhi(qreg[c].x) * bfhi(kv.x);
            s += bflo(qreg[c].y) * bflo(kv.y) + bfhi(qreg[c].y) * bfhi(kv.y);
            s += bflo(qreg[c].z) * bflo(kv.z) + bfhi(qreg[c].z) * bfhi(kv.z);
            s += bflo(qreg[c].w) * bflo(kv.w) + bfhi(qreg[c].w) * bfhi(kv.w);
        }
        sS[l][w] = s;
    }
    __syncthreads();

    if (tid < CH) {
        float mx = -1e30f;
#pragma unroll
        for (int i = 0; i < NW; i++) mx = fmaxf(mx, sS[tid][i]);
        float e[NW], sum = 0.f;
#pragma unroll
        for (int i = 0; i < NW; i++) {
            e[i] = __expf(sS[tid][i] - mx);
            sum += e[i];
        }
        const float inv = 1.f / sum;
#pragma unroll
        for (int i = 0; i < NW; i++) sS[tid][i] = e[i] * inv;
    }
    __syncthreads();

    // ctx: thread (l, wg) computes dims wg*24..wg*24+23 of line l
    {
        float p[NW];
#pragma unroll
        for (int i = 0; i < NW; i++) p[i] = sS[l][i];
        float acc[24] = {};
#pragma unroll
        for (int i = 0; i < NW; i++) {
            const int lrow = l + 4 * i + (i >= 8 ? 4 : 0);
            const unsigned short* vp = sV + lrow * 104 + wg * 24;
            const float pw = p[i];
#pragma unroll
            for (int c = 0; c < 3; c++) {
                const uint4 vv = *(const uint4*)(vp + c * 8);
                acc[c * 8 + 0] += pw * bflo(vv.x);
                acc[c * 8 + 1] += pw * bfhi(vv.x);
                acc[c * 8 + 2] += pw * bflo(vv.y);
                acc[c * 8 + 3] += pw * bfhi(vv.y);
                acc[c * 8 + 4] += pw * bflo(vv.z);
                acc[c * 8 + 5] += pw * bfhi(vv.z);
                acc[c * 8 + 6] += pw * bflo(vv.w);
                acc[c * 8 + 7] += pw * bfhi(vv.w);
            }
        }
        __syncthreads();  // done reading sQ as Q; reuse as output stage
        unsigned short* op = sQ + l * 104 + wg * 24;
#pragma unroll
        for (int c = 0; c < 12; c++) {
            *(unsigned int*)(op + c * 2) =
                (unsigned int)f2bf(acc[c * 2]) | ((unsigned int)f2bf(acc[c * 2 + 1]) << 16);
        }
    }
    __syncthreads();

    // coalesced copy-out: 64 rows x 48 uints
#pragma unroll
    for (int it = 0; it < 12; it++) {
        const int idx = tid + it * 256;
        const int row = idx / 48, cu = idx % 48;
        const unsigned int v = *(const unsigned int*)(sQ + row * 104 + cu * 2);
        *(unsigned int*)(ctx + (size_t)(n0 + row) * D + h * HD + cu * 2) = v;
    }
}

extern "C" void kernel_launch(void* const* d_in, const int* in_sizes, int n_in,
                              void* d_out, int out_size, void* d_ws, size_t ws_size,
                              hipStream_t stream) {
    const float* main_ = (const float*)d_in[0];
    const float* begin_ = (const float*)d_in[1];
    const float* end_ = (const float*)d_in[2];
    const float* in_w = (const float*)d_in[3];
    const float* in_b = (const float*)d_in[4];
    const float* out_w = (const float*)d_in[5];
    const float* out_b = (const float*)d_in[6];
    float* out = (float*)d_out;

    unsigned short* comb_bf = (unsigned short*)d_ws;        // MPAD*D
    unsigned short* w_bf = comb_bf + (size_t)MPAD * D;      // 3*D*D
    unsigned short* wo_bf = w_bf + (size_t)3 * D * D;       // D*D
    unsigned short* Qb = wo_bf + (size_t)D * D;             // NLINES*D
    unsigned short* Kb = Qb + (size_t)NLINES * D;           // MPAD*D
    unsigned short* Vb = Kb + (size_t)MPAD * D;             // MPAD*D
    unsigned short* ctxb = Vb + (size_t)MPAD * D;           // NLINES*D

    convert_comb<<<MPAD * (D / 4) / 256, 256, 0, stream>>>(main_, begin_, end_, comb_bf);
    convert_f2bf<<<3 * D * D / 1024, 256, 0, stream>>>(in_w, w_bf);
    convert_f2bf<<<D * D / 1024, 256, 0, stream>>>(out_w, wo_bf);
    qkv_gemm<<<dim3(D / 128, MPAD / 128, 3), 256, 0, stream>>>(comb_bf, w_bf, in_b, Qb, Kb, Vb);
    attn_kernel<<<dim3(NLINES / CH, NH), 256, 0, stream>>>(Qb, Kb, Vb, ctxb);
    out_gemm<<<dim3(D / 128, NLINES / 128), 256, 0, stream>>>(ctxb, wo_bf, out_b, main_, out);
}